// Round 3
// baseline (1336.023 us; speedup 1.0000x reference)
//
#include <hip/hip_runtime.h>
#include <hip/hip_cooperative_groups.h>
#include <math.h>

namespace cg = cooperative_groups;

#define N_NODES 10000
#define N_EDGES 160000
#define E2 (N_EDGES + N_NODES)
#define HIDDEN 128
#define NBGRAPH 32
#define LN_EPS 1e-5f

// cooperative mega-kernel geometry: 4-wave blocks, 4 blocks/CU guaranteed
// by __launch_bounds__(256,4) (VGPR <= 128), 1024 = 4 * 256 CUs exactly.
#define NBLK 1024
#define NTHR 256
#define NTOT (NBLK * NTHR)        // 262144 threads
#define NWAVES (NTOT / 64)        // 4096 waves

// flat-tid region boundaries for the preamble phase
#define T_INPUT (N_NODES * HIDDEN)                 // 1,280,000
#define T_HIST  (T_INPUT + N_EDGES)                // +160,000
#define T_CONV  (T_HIST + 3 * 512 * 128)           // +196,608
#define T_BOUND (T_CONV + N_NODES)                 // +10,000
#define T_TOTAL T_BOUND

typedef __attribute__((ext_vector_type(8))) short bf16x8;
typedef __attribute__((ext_vector_type(4))) float f32x4;

__device__ __forceinline__ unsigned short f2bf(float f) {
    unsigned int u = __float_as_uint(f);
    u += 0x7fffu + ((u >> 16) & 1u);       // RNE
    return (unsigned short)(u >> 16);
}
__device__ __forceinline__ float bf2f_lo(unsigned int u) { return __uint_as_float(u << 16); }
__device__ __forceinline__ float bf2f_hi(unsigned int u) { return __uint_as_float(u & 0xffff0000u); }

struct Params {
    const float* x; const int* ei; const int* batch;
    const float* node_W; const float* node_b; const float* Ws;
    const float* att_s; const float* att_d;
    const float* biases; const float* ln_g; const float* ln_b;
    float* h; float* gout;
    int* rowptr; int* cursor; int* counts; int* csr;
    int* gstart; int* gend;
    float* a_src; float* a_dst;
    unsigned short* hb;   // [N][512] bf16 gather buffer (h @ W, all 4 heads)
    unsigned short* hbx;  // [N][128] bf16 of h (gemm A operand)
    unsigned short* Btb;  // [3][512][128] bf16 transposed weights
};

// ---------------- phase bodies (shared between mega and fallback kernels) ----------

__device__ __forceinline__ void pre_item(const Params& P, int t) {
    if (t < T_INPUT) {
        int n = t >> 7, c = t & 127;
        float s = P.node_b[c];
        #pragma unroll
        for (int k = 0; k < 5; k++) s += P.x[n * 5 + k] * P.node_W[k * HIDDEN + c];
        float r = fmaxf(s, 0.f);
        P.h[t] = r;
        P.hbx[t] = f2bf(r);
    } else if (t < T_HIST) {
        int e = t - T_INPUT;
        atomicAdd(&P.counts[P.ei[N_EDGES + e]], 1);
    } else if (t < T_CONV) {
        int i = t - T_HIST;
        int l = i >> 16, rem = i & 65535;
        int n = rem >> 7, k = rem & 127;
        P.Btb[i] = f2bf(P.Ws[l * 65536 + k * 512 + n]);
    } else if (t < T_BOUND) {
        int n = t - T_CONV;
        int bb = P.batch[n];
        if (n == 0 || P.batch[n - 1] != bb) P.gstart[bb] = n;
        if (n == N_NODES - 1 || P.batch[n + 1] != bb) P.gend[bb] = n + 1;
    }
}

// prefix scan (+1 self-loop per node); re-reads counts to avoid big local array
template <int NT>
__device__ __forceinline__ void scan_body(const Params& P, int tid) {
    __shared__ int sums[NT];
    const int PER = (N_NODES + NT - 1) / NT;
    int s = 0;
    for (int i = 0; i < PER; i++) {
        int idx = tid * PER + i;
        if (idx < N_NODES) s += P.counts[idx] + 1;
    }
    sums[tid] = s;
    __syncthreads();
    for (int off = 1; off < NT; off <<= 1) {
        int v = (tid >= off) ? sums[tid - off] : 0;
        __syncthreads();
        sums[tid] += v;
        __syncthreads();
    }
    int run = (tid > 0) ? sums[tid - 1] : 0;
    for (int i = 0; i < PER; i++) {
        int idx = tid * PER + i;
        if (idx < N_NODES) {
            P.rowptr[idx] = run;
            P.cursor[idx] = run;
            run += P.counts[idx] + 1;
        }
    }
    if (tid == NT - 1) P.rowptr[N_NODES] = sums[NT - 1];
}

__device__ __forceinline__ void scatter_item(const Params& P, int e) {
    if (e < N_EDGES) {
        int s = P.ei[e], d = P.ei[N_EDGES + e];
        int pos = atomicAdd(&P.cursor[d], 1);
        P.csr[pos] = s;
    } else if (e < E2) {
        int n = e - N_EDGES;
        int pos = atomicAdd(&P.cursor[n], 1);
        P.csr[pos] = n;
    }
}

// GEMM + attention scores: one wave owns a 16-row x 128-col (one head) tile.
__device__ __forceinline__ void gemm_att_tiles(const Params& P, int l, int wid,
                                               int wstride, int lane) {
    const unsigned short* Ab = P.hbx;
    const unsigned short* Bt = P.Btb + (size_t)l * 512 * 128;
    const float* ws = P.att_s + l * 512;
    const float* wd = P.att_d + l * 512;
    unsigned short* Cb = P.hb;
    const int q = lane >> 4, u = lane & 15;
    // 625 row-tiles (10000/16 exact) x 4 heads = 2500 wave-tiles
    for (int t = wid; t < 2500; t += wstride) {
        int hh = t & 3;
        int mbase = (t >> 2) * 16;
        int colbase = hh * 128;
        bf16x8 a[4];
        const unsigned short* ap = Ab + (size_t)(mbase + u) * 128 + q * 8;
        #pragma unroll
        for (int k0 = 0; k0 < 4; k0++) a[k0] = *(const bf16x8*)(ap + k0 * 32);
        f32x4 acc[8];
        #pragma unroll
        for (int nb = 0; nb < 8; nb++) acc[nb] = (f32x4){0.f, 0.f, 0.f, 0.f};
        #pragma unroll
        for (int nb = 0; nb < 8; nb++) {
            const unsigned short* bp = Bt + (size_t)(colbase + nb * 16 + u) * 128 + q * 8;
            #pragma unroll
            for (int k0 = 0; k0 < 4; k0++) {
                bf16x8 bfr = *(const bf16x8*)(bp + k0 * 32);
                acc[nb] = __builtin_amdgcn_mfma_f32_16x16x32_bf16(a[k0], bfr, acc[nb], 0, 0, 0);
            }
        }
        #pragma unroll
        for (int nb = 0; nb < 8; nb++) {
            int col = colbase + nb * 16 + u;
            #pragma unroll
            for (int r = 0; r < 4; r++)
                Cb[(size_t)(mbase + q * 4 + r) * 512 + col] = f2bf(acc[nb][r]);
        }
        float ps[4] = {}, pd[4] = {};
        #pragma unroll
        for (int nb = 0; nb < 8; nb++) {
            float wsv = ws[hh * 128 + nb * 16 + u];
            float wdv = wd[hh * 128 + nb * 16 + u];
            #pragma unroll
            for (int r = 0; r < 4; r++) { ps[r] += acc[nb][r] * wsv; pd[r] += acc[nb][r] * wdv; }
        }
        #pragma unroll
        for (int d = 1; d < 16; d <<= 1) {
            #pragma unroll
            for (int r = 0; r < 4; r++) {
                ps[r] += __shfl_xor(ps[r], d);
                pd[r] += __shfl_xor(pd[r], d);
            }
        }
        if (u == 0) {
            #pragma unroll
            for (int r = 0; r < 4; r++) {
                int row = mbase + q * 4 + r;
                P.a_src[row * 4 + hh] = ps[r];
                P.a_dst[row * 4 + hh] = pd[r];
            }
        }
    }
}

// aggregate + head-mean + LN + relu + residual (verified r7 online-softmax body)
__device__ __forceinline__ void agg_nodes(const Params& P, int l, int wid,
                                          int wstride, int lane) {
    const uint4* hb4 = (const uint4*)P.hb;
    const float* bias = P.biases + l * HIDDEN;
    const float* lng  = P.ln_g + l * HIDDEN;
    const float* lnb  = P.ln_b + l * HIDDEN;
    const int hl = lane >> 4, pos = lane & 15;
    for (int n = wid; n < N_NODES; n += wstride) {
        int off = P.rowptr[n];
        int deg = P.rowptr[n + 1] - off;
        float adn = P.a_dst[n * 4 + hl];
        float m = -INFINITY, denom = 0.f;
        float o[8] = {};
        for (int base = 0; base < deg; base += 64) {
            int cnt = min(64, deg - base);
            int s = (lane < cnt) ? P.csr[off + base + lane] : 0;
            int si = __shfl(s, 0);
            uint4 uu = hb4[(size_t)si * 64 + lane];
            float av = P.a_src[si * 4 + hl];
            for (int i = 0; i < cnt; i++) {
                int inext = (i + 1 < cnt) ? i + 1 : i;
                int sj = __shfl(s, inext);
                uint4 un = hb4[(size_t)sj * 64 + lane];
                float an = P.a_src[sj * 4 + hl];
                float tt = av + adn;
                float e = tt > 0.f ? tt : 0.2f * tt;
                float nm = fmaxf(m, e);
                float sc = __expf(m - nm);           // first edge: exp(-inf) = 0
                float p = __expf(e - nm);
                denom = denom * sc + p;
                o[0] = o[0] * sc + p * bf2f_lo(uu.x);
                o[1] = o[1] * sc + p * bf2f_hi(uu.x);
                o[2] = o[2] * sc + p * bf2f_lo(uu.y);
                o[3] = o[3] * sc + p * bf2f_hi(uu.y);
                o[4] = o[4] * sc + p * bf2f_lo(uu.z);
                o[5] = o[5] * sc + p * bf2f_hi(uu.z);
                o[6] = o[6] * sc + p * bf2f_lo(uu.w);
                o[7] = o[7] * sc + p * bf2f_hi(uu.w);
                m = nm;
                uu = un; av = an;
            }
        }
        float inv = 1.f / (denom + 1e-16f);
        #pragma unroll
        for (int k = 0; k < 8; k++) o[k] *= inv;
        #pragma unroll
        for (int k = 0; k < 8; k++) {
            o[k] += __shfl_xor(o[k], 16);
            o[k] += __shfl_xor(o[k], 32);
        }
        float v[8], sv = 0.f, sq = 0.f;
        #pragma unroll
        for (int k = 0; k < 8; k++) {
            float b = bias[8 * pos + k];
            v[k] = 0.25f * o[k] + b;
            sv += v[k]; sq += v[k] * v[k];
        }
        #pragma unroll
        for (int d = 8; d > 0; d >>= 1) {
            sv += __shfl_xor(sv, d);
            sq += __shfl_xor(sq, d);
        }
        float mu = sv * (1.f / 128.f);
        float var = sq * (1.f / 128.f) - mu * mu;
        float rs = rsqrtf(var + LN_EPS);
        if (hl == 0) {
            float* hrow = P.h + (size_t)n * 128 + 8 * pos;
            float4 old0 = *(const float4*)(hrow);
            float4 old1 = *(const float4*)(hrow + 4);
            float r[8];
            #pragma unroll
            for (int k = 0; k < 8; k++) {
                float y = (v[k] - mu) * rs * lng[8 * pos + k] + lnb[8 * pos + k];
                r[k] = fmaxf(y, 0.f);
            }
            float w[8] = {r[0] + old0.x, r[1] + old0.y, r[2] + old0.z, r[3] + old0.w,
                          r[4] + old1.x, r[5] + old1.y, r[6] + old1.z, r[7] + old1.w};
            *(float4*)(hrow) = make_float4(w[0], w[1], w[2], w[3]);
            *(float4*)(hrow + 4) = make_float4(w[4], w[5], w[6], w[7]);
            ushort4 p0, p1;
            p0.x = f2bf(w[0]); p0.y = f2bf(w[1]); p0.z = f2bf(w[2]); p0.w = f2bf(w[3]);
            p1.x = f2bf(w[4]); p1.y = f2bf(w[5]); p1.z = f2bf(w[6]); p1.w = f2bf(w[7]);
            unsigned short* hbrow = P.hbx + (size_t)n * 128 + 8 * pos;
            *(ushort4*)(hbrow) = p0;
            *(ushort4*)(hbrow + 4) = p1;
        }
    }
}

__device__ __forceinline__ void pool_chunks(const Params& P, int vp, int vstride, int c) {
    const int nchunks = (N_NODES + 31) / 32;
    for (int chunk = vp; chunk < nchunks; chunk += vstride) {
        int n0 = chunk * 32;
        int nend = min(n0 + 32, N_NODES);
        int cur = P.batch[n0];
        float acc = 0.f;
        for (int n = n0; n < nend; n++) {
            int b = P.batch[n];
            if (b != cur) {
                float inv = 1.f / (float)max(P.gend[cur] - P.gstart[cur], 1);
                atomicAdd(&P.gout[cur * HIDDEN + c], acc * inv);
                acc = 0.f; cur = b;
            }
            acc += P.h[(size_t)n * HIDDEN + c];
        }
        float inv = 1.f / (float)max(P.gend[cur] - P.gstart[cur], 1);
        atomicAdd(&P.gout[cur * HIDDEN + c], acc * inv);
    }
}

// ---------------- cooperative mega-kernel ----------------
__global__ __launch_bounds__(NTHR, 4) void mega(Params P) {
    cg::grid_group grid = cg::this_grid();
    const int tid = threadIdx.x;
    const int bid = blockIdx.x;
    const int gtid = bid * NTHR + tid;
    const int lane = tid & 63;
    const int gwid = (gtid >> 6);

    // phase A: input proj + edge hist + weight conv + graph bounds
    for (int t = gtid; t < T_TOTAL; t += NTOT) pre_item(P, t);
    grid.sync();

    // phase B: prefix scan (block 0 only)
    if (bid == 0) scan_body<NTHR>(P, tid);
    grid.sync();

    // phase C: CSR scatter (+self-loops), then GEMM layer 0 (disjoint data)
    for (int e = gtid; e < E2; e += NTOT) scatter_item(P, e);
    gemm_att_tiles(P, 0, gwid, NWAVES, lane);
    grid.sync();

    agg_nodes(P, 0, gwid, NWAVES, lane);
    grid.sync();
    gemm_att_tiles(P, 1, gwid, NWAVES, lane);
    grid.sync();
    agg_nodes(P, 1, gwid, NWAVES, lane);
    grid.sync();
    gemm_att_tiles(P, 2, gwid, NWAVES, lane);
    grid.sync();
    agg_nodes(P, 2, gwid, NWAVES, lane);
    grid.sync();

    // phase D: graph mean pool
    pool_chunks(P, gtid >> 7, NTOT >> 7, gtid & 127);
}

// ---------------- fallback multi-kernel path (if cooperative launch rejected) ------
__global__ __launch_bounds__(256) void fb_pre(Params P) {
    pre_item(P, blockIdx.x * 256 + threadIdx.x);
}
__global__ void fb_scan(Params P) { scan_body<1024>(P, threadIdx.x); }
__global__ __launch_bounds__(256) void fb_scatter(Params P) {
    scatter_item(P, blockIdx.x * 256 + threadIdx.x);
}
__global__ __launch_bounds__(256) void fb_gemm(Params P, int l) {
    int wid = blockIdx.x * 4 + (threadIdx.x >> 6);
    gemm_att_tiles(P, l, wid, gridDim.x * 4, threadIdx.x & 63);
}
__global__ __launch_bounds__(256) void fb_agg(Params P, int l) {
    int wid = blockIdx.x * 4 + (threadIdx.x >> 6);
    agg_nodes(P, l, wid, gridDim.x * 4, threadIdx.x & 63);
}
__global__ __launch_bounds__(128) void fb_pool(Params P) {
    pool_chunks(P, blockIdx.x, gridDim.x, threadIdx.x);
}

extern "C" void kernel_launch(void* const* d_in, const int* in_sizes, int n_in,
                              void* d_out, int out_size, void* d_ws, size_t ws_size,
                              hipStream_t stream) {
    Params P;
    P.x      = (const float*)d_in[0];
    P.ei     = (const int*)d_in[1];
    P.batch  = (const int*)d_in[2];
    P.node_W = (const float*)d_in[3];
    P.node_b = (const float*)d_in[4];
    P.Ws     = (const float*)d_in[5];
    P.att_s  = (const float*)d_in[6];
    P.att_d  = (const float*)d_in[7];
    P.biases = (const float*)d_in[8];
    P.ln_g   = (const float*)d_in[9];
    P.ln_b   = (const float*)d_in[10];

    float* out = (float*)d_out;
    P.h    = out;
    P.gout = out + (size_t)N_NODES * HIDDEN;

    char* w = (char*)d_ws;
    auto carve = [&](size_t bytes) {
        void* p = (void*)w;
        w += (bytes + 255) & ~(size_t)255;
        return p;
    };
    P.rowptr = (int*)carve((N_NODES + 1) * sizeof(int));
    P.cursor = (int*)carve(N_NODES * sizeof(int));
    P.counts = (int*)carve(N_NODES * sizeof(int));
    P.csr    = (int*)carve((E2 + 16) * sizeof(int));
    P.gstart = (int*)carve(NBGRAPH * sizeof(int));
    P.gend   = (int*)carve(NBGRAPH * sizeof(int));
    P.a_src  = (float*)carve((size_t)N_NODES * 4 * sizeof(float));
    P.a_dst  = (float*)carve((size_t)N_NODES * 4 * sizeof(float));
    P.hb     = (unsigned short*)carve((size_t)N_NODES * 512 * sizeof(unsigned short));
    P.hbx    = (unsigned short*)carve((size_t)N_NODES * HIDDEN * sizeof(unsigned short));
    P.Btb    = (unsigned short*)carve((size_t)3 * 512 * 128 * sizeof(unsigned short));

    hipMemsetAsync(P.counts, 0, N_NODES * sizeof(int), stream);
    hipMemsetAsync(P.gout, 0, NBGRAPH * HIDDEN * sizeof(float), stream);

    void* args[] = {(void*)&P};
    hipError_t cerr = hipLaunchCooperativeKernel((const void*)mega, dim3(NBLK),
                                                 dim3(NTHR), args, 0, stream);
    if (cerr != hipSuccess) {
        (void)hipGetLastError();   // clear error state; use verified multi-kernel path
        fb_pre<<<(T_TOTAL + 255) / 256, 256, 0, stream>>>(P);
        fb_scan<<<1, 1024, 0, stream>>>(P);
        fb_scatter<<<(E2 + 255) / 256, 256, 0, stream>>>(P);
        for (int l = 0; l < 3; l++) {
            fb_gemm<<<625, 256, 0, stream>>>(P, l);
            fb_agg<<<2500, 256, 0, stream>>>(P, l);
        }
        fb_pool<<<(N_NODES / 32 + 3) / 4 * 4, 128, 0, stream>>>(P);
    }
}

// Round 4
// 368.013 us; speedup vs baseline: 3.6304x; 3.6304x over previous
//
#include <hip/hip_runtime.h>
#include <math.h>

#define N_NODES 10000
#define N_EDGES 160000
#define E2 (N_EDGES + N_NODES)
#define HIDDEN 128
#define NBGRAPH 32
#define LN_EPS 1e-5f

// flat-tid region boundaries for the preamble phase
#define T_INPUT (N_NODES * HIDDEN)                 // 1,280,000
#define T_HIST  (T_INPUT + N_EDGES)                // +160,000
#define T_CONV  (T_HIST + 3 * 512 * 128)           // +196,608
#define T_BOUND (T_CONV + N_NODES)                 // +10,000
#define T_TOTAL T_BOUND

typedef __attribute__((ext_vector_type(8))) short bf16x8;
typedef __attribute__((ext_vector_type(4))) float f32x4;

__device__ __forceinline__ unsigned short f2bf(float f) {
    unsigned int u = __float_as_uint(f);
    u += 0x7fffu + ((u >> 16) & 1u);       // RNE
    return (unsigned short)(u >> 16);
}
__device__ __forceinline__ float bf2f_lo(unsigned int u) { return __uint_as_float(u << 16); }
__device__ __forceinline__ float bf2f_hi(unsigned int u) { return __uint_as_float(u & 0xffff0000u); }

struct Params {
    const float* x; const int* ei; const int* batch;
    const float* node_W; const float* node_b; const float* Ws;
    const float* att_s; const float* att_d;
    const float* biases; const float* ln_g; const float* ln_b;
    float* h; float* gout;
    int* rowptr; int* cursor; int* counts; int* csr;
    int* gstart; int* gend;
    float* a_src; float* a_dst;
    unsigned short* hb;   // [N][512] bf16 gather buffer (h @ W, all 4 heads)
    unsigned short* hbx;  // [N][128] bf16 of h (gemm A operand)
    unsigned short* Btb;  // [3][512][128] bf16 transposed weights
};

// ---------------- kernel 1: input proj + edge hist + weight conv + graph bounds ----
__global__ __launch_bounds__(256) void k_pre(Params P) {
    int t = blockIdx.x * 256 + threadIdx.x;
    if (t < T_INPUT) {
        int n = t >> 7, c = t & 127;
        float s = P.node_b[c];
        #pragma unroll
        for (int k = 0; k < 5; k++) s += P.x[n * 5 + k] * P.node_W[k * HIDDEN + c];
        float r = fmaxf(s, 0.f);
        P.h[t] = r;
        P.hbx[t] = f2bf(r);
    } else if (t < T_HIST) {
        int e = t - T_INPUT;
        atomicAdd(&P.counts[P.ei[N_EDGES + e]], 1);
    } else if (t < T_CONV) {
        int i = t - T_HIST;
        int l = i >> 16, rem = i & 65535;
        int n = rem >> 7, k = rem & 127;
        P.Btb[i] = f2bf(P.Ws[l * 65536 + k * 512 + n]);
    } else if (t < T_BOUND) {
        int n = t - T_CONV;
        int bb = P.batch[n];
        if (n == 0 || P.batch[n - 1] != bb) P.gstart[bb] = n;
        if (n == N_NODES - 1 || P.batch[n + 1] != bb) P.gend[bb] = n + 1;
    }
}

// ---------------- kernel 2: prefix scan (+1 self-loop per node) ----------------
__global__ void k_scan(Params P) {
    const int NT = 1024;
    __shared__ int sums[NT];
    int tid = threadIdx.x;
    const int PER = (N_NODES + NT - 1) / NT;    // 10
    int s = 0;
    for (int i = 0; i < PER; i++) {
        int idx = tid * PER + i;
        if (idx < N_NODES) s += P.counts[idx] + 1;
    }
    sums[tid] = s;
    __syncthreads();
    for (int off = 1; off < NT; off <<= 1) {
        int v = (tid >= off) ? sums[tid - off] : 0;
        __syncthreads();
        sums[tid] += v;
        __syncthreads();
    }
    int run = (tid > 0) ? sums[tid - 1] : 0;
    for (int i = 0; i < PER; i++) {
        int idx = tid * PER + i;
        if (idx < N_NODES) {
            P.rowptr[idx] = run;
            P.cursor[idx] = run;
            run += P.counts[idx] + 1;
        }
    }
    if (tid == NT - 1) P.rowptr[N_NODES] = sums[NT - 1];
}

// ---------------- GEMM + attention scores (one wave = 16-row x one-head tile) ------
__device__ __forceinline__ void gemm_att_tiles(const Params& P, int l, int wid,
                                               int wstride, int lane) {
    const unsigned short* Ab = P.hbx;
    const unsigned short* Bt = P.Btb + (size_t)l * 512 * 128;
    const float* ws = P.att_s + l * 512;
    const float* wd = P.att_d + l * 512;
    unsigned short* Cb = P.hb;
    const int q = lane >> 4, u = lane & 15;
    // 625 row-tiles (10000/16 exact) x 4 heads = 2500 wave-tiles
    for (int t = wid; t < 2500; t += wstride) {
        int hh = t & 3;
        int mbase = (t >> 2) * 16;
        int colbase = hh * 128;
        bf16x8 a[4];
        const unsigned short* ap = Ab + (size_t)(mbase + u) * 128 + q * 8;
        #pragma unroll
        for (int k0 = 0; k0 < 4; k0++) a[k0] = *(const bf16x8*)(ap + k0 * 32);
        f32x4 acc[8];
        #pragma unroll
        for (int nb = 0; nb < 8; nb++) acc[nb] = (f32x4){0.f, 0.f, 0.f, 0.f};
        #pragma unroll
        for (int nb = 0; nb < 8; nb++) {
            const unsigned short* bp = Bt + (size_t)(colbase + nb * 16 + u) * 128 + q * 8;
            #pragma unroll
            for (int k0 = 0; k0 < 4; k0++) {
                bf16x8 bfr = *(const bf16x8*)(bp + k0 * 32);
                acc[nb] = __builtin_amdgcn_mfma_f32_16x16x32_bf16(a[k0], bfr, acc[nb], 0, 0, 0);
            }
        }
        #pragma unroll
        for (int nb = 0; nb < 8; nb++) {
            int col = colbase + nb * 16 + u;
            #pragma unroll
            for (int r = 0; r < 4; r++)
                Cb[(size_t)(mbase + q * 4 + r) * 512 + col] = f2bf(acc[nb][r]);
        }
        float ps[4] = {}, pd[4] = {};
        #pragma unroll
        for (int nb = 0; nb < 8; nb++) {
            float wsv = ws[hh * 128 + nb * 16 + u];
            float wdv = wd[hh * 128 + nb * 16 + u];
            #pragma unroll
            for (int r = 0; r < 4; r++) { ps[r] += acc[nb][r] * wsv; pd[r] += acc[nb][r] * wdv; }
        }
        #pragma unroll
        for (int d = 1; d < 16; d <<= 1) {
            #pragma unroll
            for (int r = 0; r < 4; r++) {
                ps[r] += __shfl_xor(ps[r], d);
                pd[r] += __shfl_xor(pd[r], d);
            }
        }
        if (u == 0) {
            #pragma unroll
            for (int r = 0; r < 4; r++) {
                int row = mbase + q * 4 + r;
                P.a_src[row * 4 + hh] = ps[r];
                P.a_dst[row * 4 + hh] = pd[r];
            }
        }
    }
}

// ---------------- kernel 3: CSR scatter (grid-strided) + layer-0 GEMM --------------
// scatter (writes csr via cursor atomics) and GEMM-0 (reads hbx/Btb, writes
// hb/a_src/a_dst) touch disjoint data; both depend only on pre+scan. Fusing
// them removes one dispatch and overlaps scatter latency under the GEMM.
__global__ __launch_bounds__(256) void k_scatter_gemm0(Params P) {
    int gtid = blockIdx.x * 256 + threadIdx.x;
    int stride = gridDim.x * 256;
    for (int e = gtid; e < E2; e += stride) {
        if (e < N_EDGES) {
            int s = P.ei[e], d = P.ei[N_EDGES + e];
            int pos = atomicAdd(&P.cursor[d], 1);
            P.csr[pos] = s;
        } else {
            int n = e - N_EDGES;
            int pos = atomicAdd(&P.cursor[n], 1);
            P.csr[pos] = n;
        }
    }
    gemm_att_tiles(P, 0, blockIdx.x * 4 + (threadIdx.x >> 6), gridDim.x * 4,
                   threadIdx.x & 63);
}

__global__ __launch_bounds__(256) void k_gemm(Params P, int l) {
    gemm_att_tiles(P, l, blockIdx.x * 4 + (threadIdx.x >> 6), gridDim.x * 4,
                   threadIdx.x & 63);
}

// ---------------- kernel 4: aggregate + head-mean + LN + relu + residual -----------
// verified r7 online-softmax body; DO_POOL=1 (last layer) fuses the graph
// mean-pool via per-node atomics (row is already in registers; saves a
// dispatch + a 5 MB re-read of h).
template <int DO_POOL>
__global__ __launch_bounds__(256) void k_agg(Params P, int l) {
    const uint4* hb4 = (const uint4*)P.hb;
    const float* bias = P.biases + l * HIDDEN;
    const float* lng  = P.ln_g + l * HIDDEN;
    const float* lnb  = P.ln_b + l * HIDDEN;
    const int lane = threadIdx.x & 63;
    const int hl = lane >> 4, pos = lane & 15;
    int n = blockIdx.x * 4 + (threadIdx.x >> 6);
    if (n >= N_NODES) return;
    int off = P.rowptr[n];
    int deg = P.rowptr[n + 1] - off;
    float adn = P.a_dst[n * 4 + hl];
    float m = -INFINITY, denom = 0.f;
    float o[8] = {};
    for (int base = 0; base < deg; base += 64) {
        int cnt = min(64, deg - base);
        int s = (lane < cnt) ? P.csr[off + base + lane] : 0;
        int si = __shfl(s, 0);
        uint4 uu = hb4[(size_t)si * 64 + lane];
        float av = P.a_src[si * 4 + hl];
        for (int i = 0; i < cnt; i++) {
            int inext = (i + 1 < cnt) ? i + 1 : i;
            int sj = __shfl(s, inext);
            uint4 un = hb4[(size_t)sj * 64 + lane];
            float an = P.a_src[sj * 4 + hl];
            float tt = av + adn;
            float e = tt > 0.f ? tt : 0.2f * tt;
            float nm = fmaxf(m, e);
            float sc = __expf(m - nm);           // first edge: exp(-inf) = 0
            float p = __expf(e - nm);
            denom = denom * sc + p;
            o[0] = o[0] * sc + p * bf2f_lo(uu.x);
            o[1] = o[1] * sc + p * bf2f_hi(uu.x);
            o[2] = o[2] * sc + p * bf2f_lo(uu.y);
            o[3] = o[3] * sc + p * bf2f_hi(uu.y);
            o[4] = o[4] * sc + p * bf2f_lo(uu.z);
            o[5] = o[5] * sc + p * bf2f_hi(uu.z);
            o[6] = o[6] * sc + p * bf2f_lo(uu.w);
            o[7] = o[7] * sc + p * bf2f_hi(uu.w);
            m = nm;
            uu = un; av = an;
        }
    }
    float inv = 1.f / (denom + 1e-16f);
    #pragma unroll
    for (int k = 0; k < 8; k++) o[k] *= inv;
    #pragma unroll
    for (int k = 0; k < 8; k++) {
        o[k] += __shfl_xor(o[k], 16);
        o[k] += __shfl_xor(o[k], 32);
    }
    float v[8], sv = 0.f, sq = 0.f;
    #pragma unroll
    for (int k = 0; k < 8; k++) {
        float b = bias[8 * pos + k];
        v[k] = 0.25f * o[k] + b;
        sv += v[k]; sq += v[k] * v[k];
    }
    #pragma unroll
    for (int d = 8; d > 0; d >>= 1) {
        sv += __shfl_xor(sv, d);
        sq += __shfl_xor(sq, d);
    }
    float mu = sv * (1.f / 128.f);
    float var = sq * (1.f / 128.f) - mu * mu;
    float rs = rsqrtf(var + LN_EPS);
    if (hl == 0) {
        float* hrow = P.h + (size_t)n * 128 + 8 * pos;
        float4 old0 = *(const float4*)(hrow);
        float4 old1 = *(const float4*)(hrow + 4);
        float r[8];
        #pragma unroll
        for (int k = 0; k < 8; k++) {
            float y = (v[k] - mu) * rs * lng[8 * pos + k] + lnb[8 * pos + k];
            r[k] = fmaxf(y, 0.f);
        }
        float w[8] = {r[0] + old0.x, r[1] + old0.y, r[2] + old0.z, r[3] + old0.w,
                      r[4] + old1.x, r[5] + old1.y, r[6] + old1.z, r[7] + old1.w};
        *(float4*)(hrow) = make_float4(w[0], w[1], w[2], w[3]);
        *(float4*)(hrow + 4) = make_float4(w[4], w[5], w[6], w[7]);
        ushort4 p0, p1;
        p0.x = f2bf(w[0]); p0.y = f2bf(w[1]); p0.z = f2bf(w[2]); p0.w = f2bf(w[3]);
        p1.x = f2bf(w[4]); p1.y = f2bf(w[5]); p1.z = f2bf(w[6]); p1.w = f2bf(w[7]);
        unsigned short* hbrow = P.hbx + (size_t)n * 128 + 8 * pos;
        *(ushort4*)(hbrow) = p0;
        *(ushort4*)(hbrow + 4) = p1;
        if (DO_POOL) {
            int g = P.batch[n];
            float ic = 1.f / (float)max(P.gend[g] - P.gstart[g], 1);
            #pragma unroll
            for (int k = 0; k < 8; k++)
                atomicAdd(&P.gout[g * HIDDEN + 8 * pos + k], w[k] * ic);
        }
    }
}

extern "C" void kernel_launch(void* const* d_in, const int* in_sizes, int n_in,
                              void* d_out, int out_size, void* d_ws, size_t ws_size,
                              hipStream_t stream) {
    Params P;
    P.x      = (const float*)d_in[0];
    P.ei     = (const int*)d_in[1];
    P.batch  = (const int*)d_in[2];
    P.node_W = (const float*)d_in[3];
    P.node_b = (const float*)d_in[4];
    P.Ws     = (const float*)d_in[5];
    P.att_s  = (const float*)d_in[6];
    P.att_d  = (const float*)d_in[7];
    P.biases = (const float*)d_in[8];
    P.ln_g   = (const float*)d_in[9];
    P.ln_b   = (const float*)d_in[10];

    float* out = (float*)d_out;
    P.h    = out;
    P.gout = out + (size_t)N_NODES * HIDDEN;

    char* w = (char*)d_ws;
    auto carve = [&](size_t bytes) {
        void* p = (void*)w;
        w += (bytes + 255) & ~(size_t)255;
        return p;
    };
    P.rowptr = (int*)carve((N_NODES + 1) * sizeof(int));
    P.cursor = (int*)carve(N_NODES * sizeof(int));
    P.counts = (int*)carve(N_NODES * sizeof(int));
    P.csr    = (int*)carve((E2 + 16) * sizeof(int));
    P.gstart = (int*)carve(NBGRAPH * sizeof(int));
    P.gend   = (int*)carve(NBGRAPH * sizeof(int));
    P.a_src  = (float*)carve((size_t)N_NODES * 4 * sizeof(float));
    P.a_dst  = (float*)carve((size_t)N_NODES * 4 * sizeof(float));
    P.hb     = (unsigned short*)carve((size_t)N_NODES * 512 * sizeof(unsigned short));
    P.hbx    = (unsigned short*)carve((size_t)N_NODES * HIDDEN * sizeof(unsigned short));
    P.Btb    = (unsigned short*)carve((size_t)3 * 512 * 128 * sizeof(unsigned short));

    hipMemsetAsync(P.counts, 0, N_NODES * sizeof(int), stream);
    hipMemsetAsync(P.gout, 0, NBGRAPH * HIDDEN * sizeof(float), stream);

    k_pre<<<(T_TOTAL + 255) / 256, 256, 0, stream>>>(P);
    k_scan<<<1, 1024, 0, stream>>>(P);
    k_scatter_gemm0<<<625, 256, 0, stream>>>(P);
    k_agg<0><<<2500, 256, 0, stream>>>(P, 0);
    k_gemm<<<625, 256, 0, stream>>>(P, 1);
    k_agg<0><<<2500, 256, 0, stream>>>(P, 1);
    k_gemm<<<625, 256, 0, stream>>>(P, 2);
    k_agg<1><<<2500, 256, 0, stream>>>(P, 2);
}